// Round 8
// baseline (111.111 us; speedup 1.0000x reference)
//
#include <hip/hip_runtime.h>
#include <hip/hip_bf16.h>

#define BB 16
#define TT 2048
#define CC 68
#define HH 64

typedef short bs4 __attribute__((ext_vector_type(4)));
typedef short short8 __attribute__((ext_vector_type(8)));
typedef float floatx4 __attribute__((ext_vector_type(4)));

static __device__ __forceinline__ unsigned short f2bf(float f) {
    union { float f; unsigned u; } v; v.f = f;
    unsigned r = v.u + 0x7fffu + ((v.u >> 16) & 1u);
    return (unsigned short)(r >> 16);
}
// pack two floats -> bf16x2, round-to-nearest-even
static __device__ __forceinline__ unsigned pk2(float a, float b) {
    unsigned ua = __builtin_bit_cast(unsigned, a);
    unsigned ub = __builtin_bit_cast(unsigned, b);
    ua += 0x7fffu + ((ua >> 16) & 1u);
    ub += 0x7fffu + ((ub >> 16) & 1u);
    return (ua >> 16) | (ub & 0xffff0000u);
}

#define GLD16(gsrc, ldsbase)                                                        \
    __builtin_amdgcn_global_load_lds(                                               \
        (const __attribute__((address_space(1))) unsigned int*)(gsrc),              \
        (__attribute__((address_space(3))) unsigned int*)(ldsbase), 16, 0, 0)

#define WAITV8 asm volatile("s_waitcnt vmcnt(8)" ::: "memory")
#define WAITV0 asm volatile("s_waitcnt vmcnt(0)" ::: "memory")
#define MEMFENCE asm volatile("" ::: "memory")

// ---------------- Kernel 0: W prep ----------------
// Wt[n][c]: n in [0,192) = K|Q|V output column, c in [0,96) zero-padded.
// Q columns pre-scaled by 0.125*log2(e) so attention uses exp2 directly.
__global__ __launch_bounds__(256) void prep_w(
        const float* __restrict__ Wk, const float* __restrict__ Wq,
        const float* __restrict__ Wv, unsigned short* __restrict__ Wt) {
    int idx = blockIdx.x * 256 + threadIdx.x;
    if (idx >= 192 * 96) return;
    int n = idx / 96, c = idx - n * 96;
    float v = 0.f;
    if (c < CC) {
        if (n < 64)       v = Wk[c * 64 + n];
        else if (n < 128) v = Wq[c * 64 + (n - 64)] * 0.18033688011112042f; // 0.125*log2e
        else              v = Wv[c * 64 + (n - 128)];
    }
    Wt[idx] = f2bf(v);
}

// ---------------- Kernel 1: QKV projection, swapped operands ----------------
// 1024 blocks x 256 thr (id = rowblk*16 + b, XCD matches attn). Block = 32 rows.
// Wave (w&1) = 16-row group, (w>>1) = nt half (6 output tiles of 16 cols).
// A = W (register-resident), B = x rows. D: col=l15=t, row=quad*4+r=outcol.
__global__ __launch_bounds__(256) void qkv_kernel(
        const float* __restrict__ x, const unsigned short* __restrict__ Wt,
        unsigned short* __restrict__ Qb, unsigned short* __restrict__ Kb,
        unsigned short* __restrict__ Vt) {
    int tid = threadIdx.x;
    int wave = tid >> 6, lane = tid & 63, quad = lane >> 4, l15 = lane & 15;
    int id = blockIdx.x;
    int b = id & 15, rowblk = id >> 4;
    int t0 = rowblk * 32 + (wave & 1) * 16;
    int nt0 = (wave >> 1) * 6;
    size_t row0 = (size_t)b * TT + t0;

    // B-frags from x: B[n=t=l15][k=c=quad*8+j]
    const float* xr = x + (row0 + l15) * CC;
    short8 xf[3];
    union { short8 s8; unsigned u[4]; } t;
    #pragma unroll
    for (int cs = 0; cs < 2; ++cs) {
        float4 f0 = *(const float4*)(xr + cs * 32 + quad * 8);
        float4 f1 = *(const float4*)(xr + cs * 32 + quad * 8 + 4);
        t.u[0] = pk2(f0.x, f0.y); t.u[1] = pk2(f0.z, f0.w);
        t.u[2] = pk2(f1.x, f1.y); t.u[3] = pk2(f1.z, f1.w);
        xf[cs] = t.s8;
    }
    {
        t.u[0] = 0; t.u[1] = 0; t.u[2] = 0; t.u[3] = 0;
        if (quad == 0) {
            float4 f = *(const float4*)(xr + 64);
            t.u[0] = pk2(f.x, f.y); t.u[1] = pk2(f.z, f.w);
        }
        xf[2] = t.s8;
    }

    // A-frags: Wt rows (L2-hot), register-resident: A[m=outcol=l15][k=c]
    short8 wf[6][3];
    #pragma unroll
    for (int nt = 0; nt < 6; ++nt)
        #pragma unroll
        for (int cs = 0; cs < 3; ++cs)
            wf[nt][cs] = *(const short8*)&Wt[((nt0 + nt) * 16 + l15) * 96 + cs * 32 + quad * 8];

    #pragma unroll
    for (int nt = 0; nt < 6; ++nt) {
        int gn = nt0 + nt;           // 0..3 K, 4..7 Q, 8..11 V
        floatx4 acc = (floatx4){0.f, 0.f, 0.f, 0.f};
        #pragma unroll
        for (int cs = 0; cs < 3; ++cs)
            acc = __builtin_amdgcn_mfma_f32_16x16x32_bf16(wf[nt][cs], xf[cs], acc, 0, 0, 0);

        if (gn < 8) {                // K/Q row-major [t][h]: t=l15, h=gn*16+quad*4+r
            unsigned short* dst = (gn < 4) ? Kb : Qb;
            int h0 = (gn & 3) * 16 + quad * 4;
            uint2 v2; v2.x = pk2(acc[0], acc[1]); v2.y = pk2(acc[2], acc[3]);
            *(uint2*)&dst[(row0 + l15) * 64 + h0] = v2;
        } else {                     // V^T [h][t]: h=(gn-8)*16+quad*4+r, t=t0+l15
            int h0 = (gn - 8) * 16 + quad * 4;
            #pragma unroll
            for (int r = 0; r < 4; ++r)
                Vt[((size_t)(b * 64 + h0 + r)) * TT + t0 + l15] = f2bf(acc[r]);
        }
    }
}

// ---------------- Kernel 2: flash attention, zero-P-roundtrip ----------------
// 512 WGs x 256 thr. id = qblk*16 + b. WG = one 64-q tile; wave = kv quarter
// (512 kv, 16 iters of BK=32). Wave-private LDS staging via global_load_lds
// (double-buffered, vmcnt(8) manual waits) -- NO barriers in K-loop.
// stage(it+2) is issued AFTER the MFMAs consume tile `it` (every ds_read has
// retired before the overwriting DMA is issued -- r4-proven ordering; issuing
// it before the MFMAs raced DMA writes against queued ds_reads).
__global__ __launch_bounds__(256) void attn_kernel(
        const unsigned short* __restrict__ Qb,
        const unsigned short* __restrict__ Kb,
        const unsigned short* __restrict__ Vt,
        float* __restrict__ out) {
    __shared__ union {
        unsigned char stg[4][2][8192];   // [wave][buf][ K 4KB | V 4KB ]
        float accL[64][66];              // combine overlay
    } u;
    __shared__ float lL[4][64];

    int tid = threadIdx.x;
    int wave = tid >> 6, lane = tid & 63, quad = lane >> 4, l15 = lane & 15;
    int id = blockIdx.x;
    int b = id & 15, qblk = id >> 4;     // XCD = b%8 (matches qkv writes)
    int q0 = qblk * 64;
    int kbase = wave * 512;              // this wave's kv quarter

    // Q fragments (B-operand of S^T): Q[q=qs*16+l15][h=kh*32+quad*8+j]
    short8 qf[4][2];
    #pragma unroll
    for (int qs = 0; qs < 4; ++qs)
        #pragma unroll
        for (int kh = 0; kh < 2; ++kh)
            qf[qs][kh] = *(const short8*)&Qb[((size_t)(b * TT + q0 + qs * 16 + l15)) * 64
                                             + kh * 32 + quad * 8];

    floatx4 acc[4][4];
    float lpart[4] = {0.f, 0.f, 0.f, 0.f};
    #pragma unroll
    for (int qs = 0; qs < 4; ++qs)
        #pragma unroll
        for (int hb = 0; hb < 4; ++hb) acc[qs][hb] = (floatx4){0.f, 0.f, 0.f, 0.f};

    // stage tile `it` (32 kv) into buf p: K 4 GLD16 (16B-block swizzle c^(kv&7)),
    // V 4 GLD16 (16B-block swizzle c^((h>>1)&3)).
    auto stage = [&](int it, int p) {
        unsigned char* base = u.stg[wave][p];
        int kt = kbase + it * 32;
        #pragma unroll
        for (int i2 = 0; i2 < 4; ++i2) {
            int ci = i2 * 64 + lane;
            int kv = ci >> 3, c = (ci & 7) ^ (kv & 7);
            GLD16(Kb + ((size_t)(b * TT + kt + kv) * 64 + c * 8), base + i2 * 1024);
        }
        #pragma unroll
        for (int i2 = 0; i2 < 4; ++i2) {
            int ci = i2 * 64 + lane;
            int h = ci >> 2, blkk = (ci & 3) ^ ((h >> 1) & 3);
            GLD16(Vt + ((size_t)(b * 64 + h) * TT + kt + blkk * 8), base + 4096 + i2 * 1024);
        }
    };

    stage(0, 0);
    stage(1, 1);

    for (int it = 0; it < 16; ++it) {
        if (it < 15) { WAITV8; } else { WAITV0; }
        int p = it & 1;
        const unsigned char* Kbuf = u.stg[wave][p];
        const unsigned char* Vbuf = Kbuf + 4096;

        // K frags (A of S^T): K[kv=ks*16+l15][h=kh*32+quad*8+j], deswizzled
        short8 kf[2][2];
        #pragma unroll
        for (int ks = 0; ks < 2; ++ks)
            #pragma unroll
            for (int kh = 0; kh < 2; ++kh) {
                int kvr = ks * 16 + l15;
                kf[ks][kh] = *(const short8*)(Kbuf + kvr * 128
                                              + (((kh * 4 + quad) ^ (kvr & 7)) * 16));
            }
        // V frags: 8B chunks g=quad (kv sub0) and g=quad+4 (kv sub1), deswizzled
        union { short8 s8; bs4 s4[2]; } vf[4];
        #pragma unroll
        for (int hb = 0; hb < 4; ++hb) {
            int h = hb * 16 + l15;
            int a0 = h * 64 + ((quad ^ (h & 6)) * 8);
            vf[hb].s4[0] = *(const bs4*)(Vbuf + a0);
            vf[hb].s4[1] = *(const bs4*)(Vbuf + (a0 ^ 32));
        }

        // S^T: D[m=kv=quad*4+r][n=q=l15] per (qs,ks) 16x16 tile
        floatx4 s[4][2];
        #pragma unroll
        for (int qs = 0; qs < 4; ++qs)
            #pragma unroll
            for (int ks = 0; ks < 2; ++ks) {
                floatx4 z = (floatx4){0.f, 0.f, 0.f, 0.f};
                z = __builtin_amdgcn_mfma_f32_16x16x32_bf16(kf[ks][0], qf[qs][0], z, 0, 0, 0);
                z = __builtin_amdgcn_mfma_f32_16x16x32_bf16(kf[ks][1], qf[qs][1], z, 0, 0, 0);
                s[qs][ks] = z;
            }

        // exp2 in-lane -> P A-frag directly (k-slot j: 0-3 = ks0 r0-3, 4-7 = ks1);
        // V staged with the matching slot permutation, so PV contracts correctly.
        #pragma unroll
        for (int qs = 0; qs < 4; ++qs) {
            float e0 = __builtin_amdgcn_exp2f(s[qs][0][0]);
            float e1 = __builtin_amdgcn_exp2f(s[qs][0][1]);
            float e2 = __builtin_amdgcn_exp2f(s[qs][0][2]);
            float e3 = __builtin_amdgcn_exp2f(s[qs][0][3]);
            float e4 = __builtin_amdgcn_exp2f(s[qs][1][0]);
            float e5 = __builtin_amdgcn_exp2f(s[qs][1][1]);
            float e6 = __builtin_amdgcn_exp2f(s[qs][1][2]);
            float e7 = __builtin_amdgcn_exp2f(s[qs][1][3]);
            lpart[qs] += ((e0 + e1) + (e2 + e3)) + ((e4 + e5) + (e6 + e7));
            union { short8 s8; unsigned u[4]; } pw;
            pw.u[0] = pk2(e0, e1); pw.u[1] = pk2(e2, e3);
            pw.u[2] = pk2(e4, e5); pw.u[3] = pk2(e6, e7);
            #pragma unroll
            for (int hb = 0; hb < 4; ++hb)
                acc[qs][hb] = __builtin_amdgcn_mfma_f32_16x16x32_bf16(pw.s8, vf[hb].s8, acc[qs][hb], 0, 0, 0);
        }

        // prefetch AFTER all consumption of buf p (same parity as it+2)
        MEMFENCE;
        if (it + 2 < 16) stage(it + 2, p);
    }

    // row sums across quads
    #pragma unroll
    for (int qs = 0; qs < 4; ++qs) {
        float v = lpart[qs];
        v += __shfl_xor(v, 16);
        v += __shfl_xor(v, 32);
        lpart[qs] = v;
    }
    if (quad == 0) {
        #pragma unroll
        for (int qs = 0; qs < 4; ++qs) lL[wave][qs * 16 + l15] = lpart[qs];
    }
    __syncthreads();   // all quarters done (each wave's vmcnt drained); lL visible

    // combine 4 kv-quarter partials: acc layout D[m=q=qs*16+quad*4+r][n=h=hb*16+l15]
    if (wave == 3) {
        #pragma unroll
        for (int qs = 0; qs < 4; ++qs)
            #pragma unroll
            for (int hb = 0; hb < 4; ++hb)
                #pragma unroll
                for (int r = 0; r < 4; ++r)
                    u.accL[qs * 16 + quad * 4 + r][hb * 16 + l15] = acc[qs][hb][r];
    }
    __syncthreads();
    if (wave == 2) {
        #pragma unroll
        for (int qs = 0; qs < 4; ++qs)
            #pragma unroll
            for (int hb = 0; hb < 4; ++hb)
                #pragma unroll
                for (int r = 0; r < 4; ++r)
                    u.accL[qs * 16 + quad * 4 + r][hb * 16 + l15] += acc[qs][hb][r];
    }
    __syncthreads();
    if (wave == 1) {
        #pragma unroll
        for (int qs = 0; qs < 4; ++qs)
            #pragma unroll
            for (int hb = 0; hb < 4; ++hb)
                #pragma unroll
                for (int r = 0; r < 4; ++r)
                    u.accL[qs * 16 + quad * 4 + r][hb * 16 + l15] += acc[qs][hb][r];
    }
    __syncthreads();
    if (wave == 0) {
        #pragma unroll
        for (int qs = 0; qs < 4; ++qs) {
            float rl[4];
            #pragma unroll
            for (int r = 0; r < 4; ++r) {
                int ql = qs * 16 + quad * 4 + r;
                rl[r] = 1.0f / (((lL[0][ql] + lL[1][ql]) + (lL[2][ql] + lL[3][ql])));
            }
            #pragma unroll
            for (int hb = 0; hb < 4; ++hb)
                #pragma unroll
                for (int r = 0; r < 4; ++r) {
                    int ql = qs * 16 + quad * 4 + r;
                    float tot = acc[qs][hb][r] + u.accL[ql][hb * 16 + l15];
                    out[((size_t)(b * TT + q0 + ql)) * 64 + hb * 16 + l15] = tot * rl[r];
                }
        }
    }
}

extern "C" void kernel_launch(void* const* d_in, const int* in_sizes, int n_in,
                              void* d_out, int out_size, void* d_ws, size_t ws_size,
                              hipStream_t stream) {
    const float* x  = (const float*)d_in[0];
    const float* Wk = (const float*)d_in[1];
    const float* Wq = (const float*)d_in[2];
    const float* Wv = (const float*)d_in[3];

    unsigned short* Qb = (unsigned short*)d_ws;
    unsigned short* Kb = Qb + (size_t)BB * TT * HH;
    unsigned short* Vt = Kb + (size_t)BB * TT * HH;
    unsigned short* Wt = Vt + (size_t)BB * TT * HH;
    float* out = (float*)d_out;

    prep_w<<<dim3(72), dim3(256), 0, stream>>>(Wk, Wq, Wv, Wt);
    qkv_kernel<<<dim3(2 * BB * TT / 64), dim3(256), 0, stream>>>(x, Wt, Qb, Kb, Vt);
    attn_kernel<<<dim3(BB * (TT / 64)), dim3(256), 0, stream>>>(Qb, Kb, Vt, out);
}